// Round 8
// baseline (34.799 us; speedup 1.0000x reference)
//
#include <hip/hip_runtime.h>

#define NC 5
#define NB 2
#define SPATIAL (128*128*128)
#define TILE_VOX 512                    // voxels per tile
#define NTILES (SPATIAL/TILE_VOX)       // 4096 tiles per batch
#define SMOOTHF 1e-5f

// LDS tile layout (bytes): net c at c*2048 [0,10240); dist [10240,12288);
//                          targ [12288,16384) (4KB int64 / 2KB int32)
#define TILE_BYTES (16*1024)            // x2 buffers = 32KB/block -> 4 blocks/CU

// Discipline (hard-won):
//  R2: __launch_bounds__(256,8) -> forced 32 VGPR -> 160MB spill. Never.
//  R3: full unroll -> 68 VGPR -> over 64-VGPR cliff.
//  R4: device fence + done-counter -> 6x serialization. Never.
//  R5/R6: register-path latency-bound at ~35us regardless of TLP.
//  R7: async global_load_lds 2-phase dbuf -> 33.5us. 2 blocks/CU only.
//  R8 (this): 16KB tiles -> 4 blocks/CU; drain stalls covered by 3 peers.

__device__ __forceinline__ void async16(const char* g, char* l) {
    __builtin_amdgcn_global_load_lds(
        (const __attribute__((address_space(1))) void*)g,
        (__attribute__((address_space(3))) void*)l, 16, 0, 0);
}

__global__ __launch_bounds__(256) void dpdc_main(
    const float* __restrict__ net, const void* __restrict__ targ,
    const float* __restrict__ dist, float* __restrict__ slots, int TPB)
{
    __shared__ __align__(16) char lds[2][TILE_BYTES];
    const int b = blockIdx.y, tid = threadIdx.x;

    // int64-vs-int32 detection (uniform): first 64 u64 words of target.
    const unsigned long long tv = ((const unsigned long long*)targ)[tid & 63];
    const int t64 = (__ballot(tv >= 5ull) == 0ull);

    const char* netb  = (const char*)net  + (size_t)b * NC * SPATIAL * 4;
    const char* distb = (const char*)dist + (size_t)b * SPATIAL * 4;
    const char* targb = (const char*)targ + (size_t)b * SPATIAL * (t64 ? 8 : 4);

    const int tl0 = blockIdx.x * TPB;          // first tile of this block
    const int nchunk = t64 ? 1024 : 896;       // 16B chunks per tile

    // Per-thread staging plan: chunk q = tid + 256k; region r = q>>7.
    // Each (wave,k) lies in ONE region (64*(w+4k) aligns to 128-chunk bands),
    // so global addrs are lane-contiguous 16B and LDS dest is base+lane*16.
    const char* srcp[4];
    int sstr[4];
    bool act[4];
    #pragma unroll
    for (int k = 0; k < 4; ++k) {
        const int q = tid + 256 * k;
        act[k] = (q < nchunk);
        const int r = q >> 7;
        if (r < 5) {
            srcp[k] = netb + (size_t)r * SPATIAL * 4
                           + (size_t)tl0 * 2048 + (size_t)(q & 127) * 16;
            sstr[k] = 2048;
        } else if (r == 5) {
            srcp[k] = distb + (size_t)tl0 * 2048 + (size_t)(q & 127) * 16;
            sstr[k] = 2048;
        } else {
            const int tstr = t64 ? 4096 : 2048;
            srcp[k] = targb + (size_t)tl0 * tstr + (size_t)(q - 768) * 16;
            sstr[k] = tstr;
        }
    }

    auto stage = [&](int bf) {
        char* base = &lds[bf][0];
        #pragma unroll
        for (int k = 0; k < 4; ++k)
            if (act[k]) async16(srcp[k], base + (size_t)(tid + 256 * k) * 16);
        #pragma unroll
        for (int k = 0; k < 4; ++k) srcp[k] += sstr[k];
    };

    float tp[NC], sp[NC], cnt[NC];
    #pragma unroll
    for (int c = 0; c < NC; ++c) { tp[c] = 0.f; sp[c] = 0.f; cnt[c] = 0.f; }
    float nll = 0.f;

    stage(0);
    __syncthreads();                       // vmcnt(0) drain + barrier

    #pragma unroll 1
    for (int k = 0; k < TPB; ++k) {
        if (k + 1 < TPB) stage((k + 1) & 1);   // next tile flies under compute

        const char* base = &lds[k & 1][0];
        float2 l[NC];
        #pragma unroll
        for (int c = 0; c < NC; ++c)
            l[c] = *(const float2*)(base + c * 2048 + tid * 8);
        float2 dd = *(const float2*)(base + 10240 + tid * 8);
        int tt[2];
        if (t64) {
            ulonglong2 a = *(const ulonglong2*)(base + 12288 + tid * 16);
            tt[0] = (int)a.x; tt[1] = (int)a.y;
        } else {
            int2 a = *(const int2*)(base + 12288 + tid * 8);
            tt[0] = a.x; tt[1] = a.y;
        }
        const float* dv = (const float*)&dd;
        #pragma unroll
        for (int j = 0; j < 2; ++j) {
            float lc[NC];
            #pragma unroll
            for (int c = 0; c < NC; ++c) lc[c] = ((const float*)&l[c])[j];
            float m = fmaxf(fmaxf(fmaxf(lc[0], lc[1]), fmaxf(lc[2], lc[3])), lc[4]);
            float e[NC];
            float s = 0.f;
            #pragma unroll
            for (int c = 0; c < NC; ++c) { e[c] = __expf(lc[c] - m); s += e[c]; }
            float inv = 1.0f / s;
            int t = tt[j];
            float lsel = lc[4];
            #pragma unroll
            for (int c = 0; c < 4; ++c) lsel = (t == c) ? lc[c] : lsel;
            float pd = dv[j] * inv;
            #pragma unroll
            for (int c = 0; c < NC; ++c) {
                float p = e[c] * inv;
                sp[c] += p;
                tp[c] += (t == c) ? e[c] * pd : 0.f;
                cnt[c] += (t == c) ? 1.f : 0.f;
            }
            nll += __logf(s) - (lsel - m);
        }
        __syncthreads();               // drains next tile's loads + fences bufs
    }

    // block reduction of 16 scalars: tp[5], sp[5], cnt[5], nll
    __shared__ float red[4][16];
    float vals[16];
    #pragma unroll
    for (int c = 0; c < NC; ++c) {
        vals[c] = tp[c]; vals[5 + c] = sp[c]; vals[10 + c] = cnt[c];
    }
    vals[15] = nll;
    const int lane = tid & 63;
    const int wave = tid >> 6;
    #pragma unroll
    for (int k = 0; k < 16; ++k) {
        float v = vals[k];
        #pragma unroll
        for (int off = 32; off > 0; off >>= 1) v += __shfl_down(v, off, 64);
        if (lane == 0) red[wave][k] = v;
    }
    __syncthreads();
    if (tid < 16) {
        float v = red[0][tid] + red[1][tid] + red[2][tid] + red[3][tid];
        slots[((size_t)b * gridDim.x + blockIdx.x) * 16 + tid] = v;  // plain store
    }
}

__global__ __launch_bounds__(1024) void finalize(const float* __restrict__ slots,
                                                 int gx, float* __restrict__ out) {
    __shared__ float part[1024];
    __shared__ float tot[32];
    const int j = threadIdx.x;
    const int p = j & 31;
    const int b = p >> 4, k = p & 15;
    float s = 0.f;
    for (int slot = j >> 5; slot < gx; slot += 32)
        s += slots[((size_t)b * gx + slot) * 16 + k];
    part[j] = s;
    __syncthreads();
    if (j < 32) {
        float t = 0.f;
        #pragma unroll
        for (int m = 0; m < 32; ++m) t += part[j + 32 * m];
        tot[j] = t;
    }
    __syncthreads();
    if (j == 0) {
        float dcsum = 0.f;
        for (int bb = 0; bb < NB; ++bb)
            for (int c = 0; c < NC; ++c) {
                float tpv = tot[bb * 16 + c];
                float spv = tot[bb * 16 + 5 + c];
                float cv  = tot[bb * 16 + 10 + c];
                dcsum += (2.f * tpv + SMOOTHF) / (spv + cv + SMOOTHF);
            }
        float ce = (tot[15] + tot[31]) / (float)((size_t)NB * SPATIAL);
        out[0] = ce - dcsum / (float)(NB * NC);
    }
}

extern "C" void kernel_launch(void* const* d_in, const int* in_sizes, int n_in,
                              void* d_out, int out_size, void* d_ws, size_t ws_size,
                              hipStream_t stream) {
    const float* net  = (const float*)d_in[0];
    const void*  targ = d_in[1];
    const float* dist = (const float*)d_in[2];
    float* slots = (float*)d_ws;   // NB*gx*16 floats, fully overwritten each launch

    int gx = 512;                  // 512x2 blocks = exactly 4 resident blocks/CU
    while ((size_t)NB * gx * 16 * sizeof(float) > ws_size && gx > 1) gx >>= 1;
    const int tpb = NTILES / gx;

    dim3 grid(gx, NB);
    dpdc_main<<<grid, 256, 0, stream>>>(net, targ, dist, slots, tpb);
    finalize<<<1, 1024, 0, stream>>>(slots, gx, (float*)d_out);
}